// Round 6
// baseline (64.791 us; speedup 1.0000x reference)
//
#include <hip/hip_runtime.h>

#define SS 4096
#define DD 1024
#define EE 128
#define SCALE 0.08838834764831845f   // 1/sqrt(128)

typedef __bf16 bf16x8 __attribute__((ext_vector_type(8)));
typedef float  f32x4  __attribute__((ext_vector_type(4)));

__device__ __forceinline__ void gload16(const void* g, void* l) {
  __builtin_amdgcn_global_load_lds(
      (const __attribute__((address_space(1))) void*)g,
      (__attribute__((address_space(3))) void*)l, 16, 0, 0);
}

// ---------------------------------------------------------------------------
// K0: cast W (q|k|v, each 128x1024 fp32) to bf16 Wb[384][1024].  ~0.5 us.
// grid (64, 3) x 256 thr, 8 elems/thread.
// ---------------------------------------------------------------------------
__global__ __launch_bounds__(256) void wcast_kernel(
    const float* __restrict__ qW, const float* __restrict__ kW,
    const float* __restrict__ vW, __bf16* __restrict__ Wb)
{
  const int m = blockIdx.y;
  const float* src = (m == 0) ? qW : (m == 1 ? kW : vW);
  const size_t o = ((size_t)blockIdx.x * 256 + threadIdx.x) * 8;
  float4 u0 = *(const float4*)&src[o];
  float4 u1 = *(const float4*)&src[o + 4];
  bf16x8 v = { (__bf16)u0.x, (__bf16)u0.y, (__bf16)u0.z, (__bf16)u0.w,
               (__bf16)u1.x, (__bf16)u1.y, (__bf16)u1.z, (__bf16)u1.w };
  *(bf16x8*)&Wb[(size_t)m * EE * DD + o] = v;
}

// ---------------------------------------------------------------------------
// K1: fused QKV projection.  BM=64, BN=64, BK=64; grid 768 (3 blocks/CU),
// 256 thr (4 waves, wave=32x32).  A: x fp32 via global_load_lds, cvt after
// ds_read.  B: Wb bf16 via global_load_lds.  Double-buffered, 1 barrier/step.
// XCD-chunked swizzle: ids 0..95 -> XCD0 = rtiles 0..15 x all 6 ctiles.
// ctile 0,1 -> Q (+bias, row-major); 2,3 -> KT; 4,5 -> VT (LDS transpose).
// ---------------------------------------------------------------------------
__global__ __launch_bounds__(256) void proj_kernel(
    const float* __restrict__ x, const __bf16* __restrict__ Wb,
    const float* __restrict__ qB, const float* __restrict__ kB,
    const float* __restrict__ vB,
    __bf16* __restrict__ Qbf, __bf16* __restrict__ KT, __bf16* __restrict__ VT)
{
  __shared__ __attribute__((aligned(16))) float  ldsA[2][64 * 64];  // 32 KB
  __shared__ __attribute__((aligned(16))) __bf16 ldsB[2][64 * 64];  // 16 KB

  const int tid  = threadIdx.x;
  const int w    = tid >> 6, lane = tid & 63;
  const int l15  = lane & 15, l4 = lane >> 4;
  const int wr   = w >> 1, wc = w & 1;          // wave tile 32r x 32c

  // XCD-chunked bijective swizzle (768 % 8 == 0), then rtile-major decode
  const int id   = blockIdx.x;
  const int swz  = (id & 7) * 96 + (id >> 3);
  const int rt   = swz / 6, ct = swz % 6;
  const int row0 = rt * 64;                     // flat row [0,8192)
  const int g0   = ct * 64;                     // col base [0,384)

  // staging addresses
  const float*  gA = x  + (size_t)(row0 + w * 16 + (lane >> 4)) * DD + (lane & 15) * 4;
  const __bf16* gB = Wb + (size_t)(g0   + w * 16 + (lane >> 3)) * DD + (lane & 7) * 8;

  f32x4 acc[2][2] = {};

#define STAGE(P, T) {                                                        \
    const int k0_ = (T) * 64;                                                \
    _Pragma("unroll") for (int j = 0; j < 4; ++j)                            \
      gload16(gA + k0_ + (size_t)j * 4 * DD, &ldsA[P][(w * 16 + j * 4) * 64]); \
    _Pragma("unroll") for (int j = 0; j < 2; ++j)                            \
      gload16(gB + k0_ + (size_t)j * 8 * DD, &ldsB[P][(w * 16 + j * 8) * 64]); }

#define CVT8(LO, HI) (bf16x8){ (__bf16)(LO)[0], (__bf16)(LO)[1],             \
    (__bf16)(LO)[2], (__bf16)(LO)[3], (__bf16)(HI)[0], (__bf16)(HI)[1],      \
    (__bf16)(HI)[2], (__bf16)(HI)[3] }

#define COMPUTE(P) {                                                         \
    _Pragma("unroll") for (int ks = 0; ks < 2; ++ks) {                       \
      const int ko = ks * 32 + l4 * 8;                                       \
      bf16x8 af[2], bq[2];                                                   \
      _Pragma("unroll") for (int m = 0; m < 2; ++m) {                        \
        const int row = wr * 32 + m * 16 + l15;                              \
        f32x4 lo = *(const f32x4*)&ldsA[P][row * 64 + ko];                   \
        f32x4 hi = *(const f32x4*)&ldsA[P][row * 64 + ko + 4];               \
        af[m] = CVT8(lo, hi);                                                \
      }                                                                      \
      _Pragma("unroll") for (int n = 0; n < 2; ++n)                          \
        bq[n] = *(const bf16x8*)&ldsB[P][(wc * 32 + n * 16 + l15) * 64 + ko];\
      acc[0][0] = __builtin_amdgcn_mfma_f32_16x16x32_bf16(af[0],bq[0],acc[0][0],0,0,0); \
      acc[0][1] = __builtin_amdgcn_mfma_f32_16x16x32_bf16(af[0],bq[1],acc[0][1],0,0,0); \
      acc[1][0] = __builtin_amdgcn_mfma_f32_16x16x32_bf16(af[1],bq[0],acc[1][0],0,0,0); \
      acc[1][1] = __builtin_amdgcn_mfma_f32_16x16x32_bf16(af[1],bq[1],acc[1][1],0,0,0); \
    } }

  STAGE(0, 0);
  __syncthreads();
  for (int t = 0; t < 15; ++t) {
    STAGE((t + 1) & 1, t + 1);
    COMPUTE(t & 1);
    __syncthreads();
  }
  COMPUTE(1);
  __syncthreads();
#undef STAGE
#undef CVT8
#undef COMPUTE

  const float* bias = (g0 < 128) ? qB : (g0 < 256 ? kB : vB);
  const int bofs = (g0 < 128) ? g0 : (g0 < 256 ? g0 - 128 : g0 - 256);

  if (ct < 2) {                                  // Q: row-major store
    #pragma unroll
    for (int m = 0; m < 2; ++m)
      #pragma unroll
      for (int n = 0; n < 2; ++n) {
        const int col = wc * 32 + n * 16 + l15;
        const float bv = bias[bofs + col];
        #pragma unroll
        for (int r = 0; r < 4; ++r) {
          const int row = row0 + wr * 32 + m * 16 + l4 * 4 + r;
          Qbf[(size_t)row * EE + g0 + col] = (__bf16)(acc[m][n][r] + bv);
        }
      }
  } else {                                       // K/V: transpose via LDS
    __bf16* Tb = (__bf16*)ldsA;                  // [64 cols][64 rows chunkXOR] 8KB
    #pragma unroll
    for (int m = 0; m < 2; ++m)
      #pragma unroll
      for (int n = 0; n < 2; ++n) {
        const int tc = wc * 32 + n * 16 + l15;
        const float bv = bias[bofs + tc];
        #pragma unroll
        for (int r = 0; r < 4; ++r) {
          const int rl = wr * 32 + m * 16 + l4 * 4 + r;
          Tb[tc * 64 + (((rl >> 3) ^ (tc & 7)) << 3) + (rl & 7)] =
              (__bf16)(acc[m][n][r] + bv);
        }
      }
    __syncthreads();
    const int col = tid >> 2, p2 = tid & 3;      // 64 cols x 4 thr
    const int b = row0 >> 12, s0 = row0 & 4095;
    __bf16* dst = (ct < 4)
        ? &KT[((size_t)b * EE + (ct - 2) * 64 + col) * SS + s0]
        : &VT[((size_t)b * EE + (ct - 4) * 64 + col) * SS + s0];
    #pragma unroll
    for (int j = 0; j < 2; ++j) {
      const int ch = p2 * 2 + j;                 // 8 chunks of 8 bf16
      bf16x8 v = *(const bf16x8*)&Tb[col * 64 + ((ch ^ (col & 7)) << 3)];
      *(bf16x8*)&dst[ch * 8] = v;
    }
  }
}

// ---------------------------------------------------------------------------
// K2: partial K^T V.  grid (32 chunks, 2 batches) x 256 threads (4 waves).
// ---------------------------------------------------------------------------
__global__ __launch_bounds__(256) void ktv_kernel(
    const __bf16* __restrict__ KT, const __bf16* __restrict__ VT,
    float* __restrict__ part)
{
  const int c = blockIdx.x, b = blockIdx.y;
  const int tid = threadIdx.x;
  const int w = tid >> 6, lane = tid & 63;
  const int l15 = lane & 15, l4 = lane >> 4;
  const int s0 = c * 128;
  const __bf16* Kb = KT + (size_t)b * EE * SS;
  const __bf16* Vb = VT + (size_t)b * EE * SS;

  f32x4 acc[8][2] = {};
  #pragma unroll
  for (int ks = 0; ks < 4; ++ks) {
    const int s = s0 + ks * 32 + 8 * l4;
    bf16x8 bv[2];
    #pragma unroll
    for (int j = 0; j < 2; ++j)
      bv[j] = *(const bf16x8*)&Vb[(size_t)(w * 32 + j * 16 + l15) * SS + s];
    #pragma unroll
    for (int i = 0; i < 8; ++i) {
      bf16x8 av = *(const bf16x8*)&Kb[(size_t)(i * 16 + l15) * SS + s];
      acc[i][0] = __builtin_amdgcn_mfma_f32_16x16x32_bf16(av, bv[0], acc[i][0], 0, 0, 0);
      acc[i][1] = __builtin_amdgcn_mfma_f32_16x16x32_bf16(av, bv[1], acc[i][1], 0, 0, 0);
    }
  }
  float* P = part + (size_t)(b * 32 + c) * 16384;
  #pragma unroll
  for (int i = 0; i < 8; ++i)
    #pragma unroll
    for (int j = 0; j < 2; ++j)
      #pragma unroll
      for (int r = 0; r < 4; ++r) {
        int e = i * 16 + l4 * 4 + r;
        int f = w * 32 + j * 16 + l15;
        P[e * 128 + f] = acc[i][j][r];
      }
}

// ---------------------------------------------------------------------------
// K3: reduce 32 partials -> MT[b][f][e] = scale * sum (bf16, transposed)
// ---------------------------------------------------------------------------
__global__ __launch_bounds__(256) void reduce_kernel(
    const float* __restrict__ part, __bf16* __restrict__ MT)
{
  const int b = blockIdx.y;
  const int e = blockIdx.x * 8 + (threadIdx.x >> 5);
  const int f4 = (threadIdx.x & 31) * 4;
  f32x4 s = {};
  for (int cc = 0; cc < 32; ++cc)
    s += *(const f32x4*)&part[(size_t)(b * 32 + cc) * 16384 + e * 128 + f4];
  #pragma unroll
  for (int i = 0; i < 4; ++i)
    MT[((size_t)b * EE + f4 + i) * EE + e] = (__bf16)(SCALE * s[i]);
}

// ---------------------------------------------------------------------------
// K4: O = Q * M  (MT[f][e]).  grid (64, 2) x 256 threads.
// ---------------------------------------------------------------------------
__global__ __launch_bounds__(256) void qm_kernel(
    const __bf16* __restrict__ Qbf, const __bf16* __restrict__ MT,
    float* __restrict__ out)
{
  const int b = blockIdx.y;
  const int tid = threadIdx.x;
  const int w = tid >> 6, lane = tid & 63;
  const int l15 = lane & 15, l4 = lane >> 4;
  const int row0 = blockIdx.x * 64 + w * 16;
  const __bf16* Qb = Qbf + (size_t)b * SS * EE;
  const __bf16* Mb = MT + (size_t)b * EE * EE;

  f32x4 acc[8] = {};
  #pragma unroll
  for (int ks = 0; ks < 4; ++ks) {
    const int e = ks * 32 + 8 * l4;
    bf16x8 av = *(const bf16x8*)&Qb[(size_t)(row0 + l15) * EE + e];
    #pragma unroll
    for (int j = 0; j < 8; ++j) {
      bf16x8 bv = *(const bf16x8*)&Mb[(size_t)(j * 16 + l15) * EE + e];
      acc[j] = __builtin_amdgcn_mfma_f32_16x16x32_bf16(av, bv, acc[j], 0, 0, 0);
    }
  }
  #pragma unroll
  for (int j = 0; j < 8; ++j)
    #pragma unroll
    for (int r = 0; r < 4; ++r) {
      int srow = row0 + l4 * 4 + r;
      int f = j * 16 + l15;
      out[((size_t)b * SS + srow) * EE + f] = acc[j][r];
    }
}

extern "C" void kernel_launch(void* const* d_in, const int* in_sizes, int n_in,
                              void* d_out, int out_size, void* d_ws, size_t ws_size,
                              hipStream_t stream) {
  const float* x  = (const float*)d_in[0];
  const float* qW = (const float*)d_in[1];
  const float* qB = (const float*)d_in[2];
  const float* kW = (const float*)d_in[3];
  const float* kB = (const float*)d_in[4];
  const float* vW = (const float*)d_in[5];
  const float* vB = (const float*)d_in[6];
  float* out = (float*)d_out;

  char* base = (char*)d_ws;
  __bf16* Wb  = (__bf16*)(base);                         // 768 KB
  __bf16* Qbf = (__bf16*)(base + (1u  << 20));           // 2 MB
  __bf16* KT  = (__bf16*)(base + (3u  << 20));           // 2 MB
  __bf16* VT  = (__bf16*)(base + (5u  << 20));           // 2 MB
  float*  part= (float*) (base + (7u  << 20));           // 4 MB
  __bf16* MT  = (__bf16*)(base + (11u << 20));           // 64 KB

  wcast_kernel <<<dim3(64, 3), 256, 0, stream>>>(qW, kW, vW, Wb);
  proj_kernel  <<<dim3(768),   256, 0, stream>>>(x, Wb, qB, kB, vB, Qbf, KT, VT);
  ktv_kernel   <<<dim3(32, 2), 256, 0, stream>>>(KT, VT, part);
  reduce_kernel<<<dim3(16, 2), 256, 0, stream>>>(part, MT);
  qm_kernel    <<<dim3(64, 2), 256, 0, stream>>>(Qbf, MT, out);
}

// Round 7
// 46.767 us; speedup vs baseline: 1.3854x; 1.3854x over previous
//
#include <hip/hip_runtime.h>

#define SS 4096
#define DD 1024
#define EE 128
#define SCALE 0.08838834764831845f   // 1/sqrt(128)

typedef __bf16 bf16x8 __attribute__((ext_vector_type(8)));
typedef float  f32x4  __attribute__((ext_vector_type(4)));

__device__ __forceinline__ void gload16(const void* g, void* l) {
  __builtin_amdgcn_global_load_lds(
      (const __attribute__((address_space(1))) void*)g,
      (__attribute__((address_space(3))) void*)l, 16, 0, 0);
}

// ---------------------------------------------------------------------------
// K0: cast W (q|k|v, each 128x1024 fp32) to bf16 Wb[384][1024].  ~0.5 us.
// ---------------------------------------------------------------------------
__global__ __launch_bounds__(256) void wcast_kernel(
    const float* __restrict__ qW, const float* __restrict__ kW,
    const float* __restrict__ vW, __bf16* __restrict__ Wb)
{
  const int m = blockIdx.y;
  const float* src = (m == 0) ? qW : (m == 1 ? kW : vW);
  const size_t o = ((size_t)blockIdx.x * 256 + threadIdx.x) * 8;
  float4 u0 = *(const float4*)&src[o];
  float4 u1 = *(const float4*)&src[o + 4];
  bf16x8 v = { (__bf16)u0.x, (__bf16)u0.y, (__bf16)u0.z, (__bf16)u0.w,
               (__bf16)u1.x, (__bf16)u1.y, (__bf16)u1.z, (__bf16)u1.w };
  *(bf16x8*)&Wb[(size_t)m * EE * DD + o] = v;
}

// ---------------------------------------------------------------------------
// K1: fused QKV projection.  BM=64, BN=64, BK=64; grid 768 (3 blocks/CU),
// 256 thr (4 waves, wave=32x32).  global_load_lds staging with SOURCE-side
// XOR swizzle (linear LDS dest, swizzled global addr, swizzled ds_read):
// LDS slot (row,pos) holds chunk pos^(row&7)  [16B chunks].
// ctile 0,1 -> Q (+bias, row-major); 2,3 -> KT; 4,5 -> VT (LDS transpose).
// ---------------------------------------------------------------------------
__global__ __launch_bounds__(256) void proj_kernel(
    const float* __restrict__ x, const __bf16* __restrict__ Wb,
    const float* __restrict__ qB, const float* __restrict__ kB,
    const float* __restrict__ vB,
    __bf16* __restrict__ Qbf, __bf16* __restrict__ KT, __bf16* __restrict__ VT)
{
  __shared__ __attribute__((aligned(16))) float  ldsA[2][64 * 64];  // 32 KB
  __shared__ __attribute__((aligned(16))) __bf16 ldsB[2][64 * 64];  // 16 KB

  const int tid  = threadIdx.x;
  const int w    = tid >> 6, lane = tid & 63;
  const int l15  = lane & 15, l4 = lane >> 4;
  const int wr   = w >> 1, wc = w & 1;          // wave tile 32r x 32c

  // XCD-chunked bijective swizzle (768 % 8 == 0), rtile-major within XCD
  const int id   = blockIdx.x;
  const int swz  = (id & 7) * 96 + (id >> 3);
  const int rt   = swz / 6, ct = swz % 6;
  const int row0 = rt * 64;                     // flat row [0,8192)
  const int g0   = ct * 64;                     // col base [0,384)

  // ---- staging addresses, SOURCE-swizzled (rule #21 / m201 pattern) ----
  // A: dest row r = w*16 + j*4 + (lane>>4), dest chunk pos = lane&15.
  //    r&7 = (j&1)*4 + (lane>>4)  ->  source chunk = pos ^ (r&7).
  const int aRow = lane >> 4;                   // 0..3
  const int aPos = lane & 15;
  const int cE   = aPos ^ aRow;                 // even j
  const int cO   = aPos ^ (4 | aRow);           // odd j
  const float* gAe = x + (size_t)(row0 + w * 16 + aRow) * DD + cE * 4;
  const float* gAo = x + (size_t)(row0 + w * 16 + aRow) * DD + cO * 4;
  // B: dest row r = w*16 + j*8 + (lane>>3), pos = lane&7; r&7 = lane>>3.
  const int bRow = lane >> 3;                   // 0..7
  const int cB   = (lane & 7) ^ bRow;
  const __bf16* gB = Wb + (size_t)(g0 + w * 16 + bRow) * DD + cB * 8;

  f32x4 acc[2][2] = {};

#define STAGE(P, T) {                                                        \
    const int k0_ = (T) * 64;                                                \
    gload16(gAe + k0_,                    &ldsA[P][(w * 16 +  0) * 64]);     \
    gload16(gAo + k0_ + (size_t) 4 * DD,  &ldsA[P][(w * 16 +  4) * 64]);     \
    gload16(gAe + k0_ + (size_t) 8 * DD,  &ldsA[P][(w * 16 +  8) * 64]);     \
    gload16(gAo + k0_ + (size_t)12 * DD,  &ldsA[P][(w * 16 + 12) * 64]);     \
    gload16(gB  + k0_,                    &ldsB[P][(w * 16 +  0) * 64]);     \
    gload16(gB  + k0_ + (size_t) 8 * DD,  &ldsB[P][(w * 16 +  8) * 64]);     }

#define CVT8(LO, HI) (bf16x8){ (__bf16)(LO)[0], (__bf16)(LO)[1],             \
    (__bf16)(LO)[2], (__bf16)(LO)[3], (__bf16)(HI)[0], (__bf16)(HI)[1],      \
    (__bf16)(HI)[2], (__bf16)(HI)[3] }

#define COMPUTE(P) {                                                         \
    const int rs7 = l15 & 7;                                                 \
    _Pragma("unroll") for (int ks = 0; ks < 2; ++ks) {                       \
      bf16x8 af[2], bq[2];                                                   \
      _Pragma("unroll") for (int m = 0; m < 2; ++m) {                        \
        const int row = wr * 32 + m * 16 + l15;                              \
        const int c0 = ks * 8 + l4 * 2;                                      \
        f32x4 lo = *(const f32x4*)&ldsA[P][row * 64 + (( c0      ^ rs7) << 2)]; \
        f32x4 hi = *(const f32x4*)&ldsA[P][row * 64 + (((c0 + 1) ^ rs7) << 2)]; \
        af[m] = CVT8(lo, hi);                                                \
      }                                                                      \
      _Pragma("unroll") for (int n = 0; n < 2; ++n) {                        \
        const int row = wc * 32 + n * 16 + l15;                              \
        bq[n] = *(const bf16x8*)&ldsB[P][row * 64 + (((ks*4 + l4) ^ rs7) << 3)]; \
      }                                                                      \
      acc[0][0] = __builtin_amdgcn_mfma_f32_16x16x32_bf16(af[0],bq[0],acc[0][0],0,0,0); \
      acc[0][1] = __builtin_amdgcn_mfma_f32_16x16x32_bf16(af[0],bq[1],acc[0][1],0,0,0); \
      acc[1][0] = __builtin_amdgcn_mfma_f32_16x16x32_bf16(af[1],bq[0],acc[1][0],0,0,0); \
      acc[1][1] = __builtin_amdgcn_mfma_f32_16x16x32_bf16(af[1],bq[1],acc[1][1],0,0,0); \
    } }

  STAGE(0, 0);
  __syncthreads();
  for (int t = 0; t < 15; ++t) {
    STAGE((t + 1) & 1, t + 1);
    COMPUTE(t & 1);
    __syncthreads();
  }
  COMPUTE(1);
  __syncthreads();
#undef STAGE
#undef CVT8
#undef COMPUTE

  const float* bias = (g0 < 128) ? qB : (g0 < 256 ? kB : vB);
  const int bofs = (g0 < 128) ? g0 : (g0 < 256 ? g0 - 128 : g0 - 256);

  if (ct < 2) {                                  // Q: row-major store
    #pragma unroll
    for (int m = 0; m < 2; ++m)
      #pragma unroll
      for (int n = 0; n < 2; ++n) {
        const int col = wc * 32 + n * 16 + l15;
        const float bv = bias[bofs + col];
        #pragma unroll
        for (int r = 0; r < 4; ++r) {
          const int row = row0 + wr * 32 + m * 16 + l4 * 4 + r;
          Qbf[(size_t)row * EE + g0 + col] = (__bf16)(acc[m][n][r] + bv);
        }
      }
  } else {                                       // K/V: transpose via LDS
    __bf16* Tb = (__bf16*)ldsA;                  // [64 cols][64 rows chunkXOR]
    #pragma unroll
    for (int m = 0; m < 2; ++m)
      #pragma unroll
      for (int n = 0; n < 2; ++n) {
        const int tc = wc * 32 + n * 16 + l15;
        const float bv = bias[bofs + tc];
        #pragma unroll
        for (int r = 0; r < 4; ++r) {
          const int rl = wr * 32 + m * 16 + l4 * 4 + r;
          Tb[tc * 64 + (((rl >> 3) ^ (tc & 7)) << 3) + (rl & 7)] =
              (__bf16)(acc[m][n][r] + bv);
        }
      }
    __syncthreads();
    const int col = tid >> 2, p2 = tid & 3;      // 64 cols x 4 thr
    const int b = row0 >> 12, s0 = row0 & 4095;
    __bf16* dst = (ct < 4)
        ? &KT[((size_t)b * EE + (ct - 2) * 64 + col) * SS + s0]
        : &VT[((size_t)b * EE + (ct - 4) * 64 + col) * SS + s0];
    #pragma unroll
    for (int j = 0; j < 2; ++j) {
      const int ch = p2 * 2 + j;                 // 8 chunks of 8 bf16
      bf16x8 v = *(const bf16x8*)&Tb[col * 64 + ((ch ^ (col & 7)) << 3)];
      *(bf16x8*)&dst[ch * 8] = v;
    }
  }
}

// ---------------------------------------------------------------------------
// K2: partial K^T V.  grid (32 chunks, 2 batches) x 256 threads (4 waves).
// ---------------------------------------------------------------------------
__global__ __launch_bounds__(256) void ktv_kernel(
    const __bf16* __restrict__ KT, const __bf16* __restrict__ VT,
    float* __restrict__ part)
{
  const int c = blockIdx.x, b = blockIdx.y;
  const int tid = threadIdx.x;
  const int w = tid >> 6, lane = tid & 63;
  const int l15 = lane & 15, l4 = lane >> 4;
  const int s0 = c * 128;
  const __bf16* Kb = KT + (size_t)b * EE * SS;
  const __bf16* Vb = VT + (size_t)b * EE * SS;

  f32x4 acc[8][2] = {};
  #pragma unroll
  for (int ks = 0; ks < 4; ++ks) {
    const int s = s0 + ks * 32 + 8 * l4;
    bf16x8 bv[2];
    #pragma unroll
    for (int j = 0; j < 2; ++j)
      bv[j] = *(const bf16x8*)&Vb[(size_t)(w * 32 + j * 16 + l15) * SS + s];
    #pragma unroll
    for (int i = 0; i < 8; ++i) {
      bf16x8 av = *(const bf16x8*)&Kb[(size_t)(i * 16 + l15) * SS + s];
      acc[i][0] = __builtin_amdgcn_mfma_f32_16x16x32_bf16(av, bv[0], acc[i][0], 0, 0, 0);
      acc[i][1] = __builtin_amdgcn_mfma_f32_16x16x32_bf16(av, bv[1], acc[i][1], 0, 0, 0);
    }
  }
  float* P = part + (size_t)(b * 32 + c) * 16384;
  #pragma unroll
  for (int i = 0; i < 8; ++i)
    #pragma unroll
    for (int j = 0; j < 2; ++j)
      #pragma unroll
      for (int r = 0; r < 4; ++r) {
        int e = i * 16 + l4 * 4 + r;
        int f = w * 32 + j * 16 + l15;
        P[e * 128 + f] = acc[i][j][r];
      }
}

// ---------------------------------------------------------------------------
// K3: reduce 32 partials -> MT[b][f][e] = scale * sum (bf16, transposed)
// ---------------------------------------------------------------------------
__global__ __launch_bounds__(256) void reduce_kernel(
    const float* __restrict__ part, __bf16* __restrict__ MT)
{
  const int b = blockIdx.y;
  const int e = blockIdx.x * 8 + (threadIdx.x >> 5);
  const int f4 = (threadIdx.x & 31) * 4;
  f32x4 s = {};
  for (int cc = 0; cc < 32; ++cc)
    s += *(const f32x4*)&part[(size_t)(b * 32 + cc) * 16384 + e * 128 + f4];
  #pragma unroll
  for (int i = 0; i < 4; ++i)
    MT[((size_t)b * EE + f4 + i) * EE + e] = (__bf16)(SCALE * s[i]);
}

// ---------------------------------------------------------------------------
// K4: O = Q * M  (MT[f][e]).  grid (64, 2) x 256 threads.
// ---------------------------------------------------------------------------
__global__ __launch_bounds__(256) void qm_kernel(
    const __bf16* __restrict__ Qbf, const __bf16* __restrict__ MT,
    float* __restrict__ out)
{
  const int b = blockIdx.y;
  const int tid = threadIdx.x;
  const int w = tid >> 6, lane = tid & 63;
  const int l15 = lane & 15, l4 = lane >> 4;
  const int row0 = blockIdx.x * 64 + w * 16;
  const __bf16* Qb = Qbf + (size_t)b * SS * EE;
  const __bf16* Mb = MT + (size_t)b * EE * EE;

  f32x4 acc[8] = {};
  #pragma unroll
  for (int ks = 0; ks < 4; ++ks) {
    const int e = ks * 32 + 8 * l4;
    bf16x8 av = *(const bf16x8*)&Qb[(size_t)(row0 + l15) * EE + e];
    #pragma unroll
    for (int j = 0; j < 8; ++j) {
      bf16x8 bv = *(const bf16x8*)&Mb[(size_t)(j * 16 + l15) * EE + e];
      acc[j] = __builtin_amdgcn_mfma_f32_16x16x32_bf16(av, bv, acc[j], 0, 0, 0);
    }
  }
  #pragma unroll
  for (int j = 0; j < 8; ++j)
    #pragma unroll
    for (int r = 0; r < 4; ++r) {
      int srow = row0 + l4 * 4 + r;
      int f = j * 16 + l15;
      out[((size_t)b * SS + srow) * EE + f] = acc[j][r];
    }
}

extern "C" void kernel_launch(void* const* d_in, const int* in_sizes, int n_in,
                              void* d_out, int out_size, void* d_ws, size_t ws_size,
                              hipStream_t stream) {
  const float* x  = (const float*)d_in[0];
  const float* qW = (const float*)d_in[1];
  const float* qB = (const float*)d_in[2];
  const float* kW = (const float*)d_in[3];
  const float* kB = (const float*)d_in[4];
  const float* vW = (const float*)d_in[5];
  const float* vB = (const float*)d_in[6];
  float* out = (float*)d_out;

  char* base = (char*)d_ws;
  __bf16* Wb  = (__bf16*)(base);                         // 768 KB
  __bf16* Qbf = (__bf16*)(base + (1u  << 20));           // 2 MB
  __bf16* KT  = (__bf16*)(base + (3u  << 20));           // 2 MB
  __bf16* VT  = (__bf16*)(base + (5u  << 20));           // 2 MB
  float*  part= (float*) (base + (7u  << 20));           // 4 MB
  __bf16* MT  = (__bf16*)(base + (11u << 20));           // 64 KB

  wcast_kernel <<<dim3(64, 3), 256, 0, stream>>>(qW, kW, vW, Wb);
  proj_kernel  <<<dim3(768),   256, 0, stream>>>(x, Wb, qB, kB, vB, Qbf, KT, VT);
  ktv_kernel   <<<dim3(32, 2), 256, 0, stream>>>(KT, VT, part);
  reduce_kernel<<<dim3(16, 2), 256, 0, stream>>>(part, MT);
  qm_kernel    <<<dim3(64, 2), 256, 0, stream>>>(Qbf, MT, out);
}

// Round 8
// 42.714 us; speedup vs baseline: 1.5168x; 1.0949x over previous
//
#include <hip/hip_runtime.h>

#define SS 4096
#define DD 1024
#define EE 128
#define SCALE 0.08838834764831845f   // 1/sqrt(128)

typedef __bf16 bf16x8 __attribute__((ext_vector_type(8)));
typedef float  f32x4  __attribute__((ext_vector_type(4)));

__device__ __forceinline__ void gload16(const void* g, void* l) {
  __builtin_amdgcn_global_load_lds(
      (const __attribute__((address_space(1))) void*)g,
      (__attribute__((address_space(3))) void*)l, 16, 0, 0);
}

// ---------------------------------------------------------------------------
// K0: cast W (q|k|v, each 128x1024 fp32) to bf16 Wb[384][1024].
// ---------------------------------------------------------------------------
__global__ __launch_bounds__(256) void wcast_kernel(
    const float* __restrict__ qW, const float* __restrict__ kW,
    const float* __restrict__ vW, __bf16* __restrict__ Wb)
{
  const int m = blockIdx.y;
  const float* src = (m == 0) ? qW : (m == 1 ? kW : vW);
  const size_t o = ((size_t)blockIdx.x * 256 + threadIdx.x) * 8;
  float4 u0 = *(const float4*)&src[o];
  float4 u1 = *(const float4*)&src[o + 4];
  bf16x8 v = { (__bf16)u0.x, (__bf16)u0.y, (__bf16)u0.z, (__bf16)u0.w,
               (__bf16)u1.x, (__bf16)u1.y, (__bf16)u1.z, (__bf16)u1.w };
  *(bf16x8*)&Wb[(size_t)m * EE * DD + o] = v;
}

// ---------------------------------------------------------------------------
// K1: fused QKV projection.  BM=64, BN=96, BK=64; grid 512 (2 blocks/CU),
// 256 thr (4 waves 2x2, wave-tile 32x48: m=2 n=3 -> better A amortization).
// global_load_lds with source-side XOR swizzle (linear dest, verified R7).
// ctile cols [ct*96, ct*96+96) span Q|K|V; per-fragment routing at 128-col
// boundaries (16-col frags divide 128 evenly).
// ---------------------------------------------------------------------------
__global__ __launch_bounds__(256) void proj_kernel(
    const float* __restrict__ x, const __bf16* __restrict__ Wb,
    const float* __restrict__ qB, const float* __restrict__ kB,
    const float* __restrict__ vB,
    __bf16* __restrict__ Qbf, __bf16* __restrict__ KT, __bf16* __restrict__ VT)
{
  __shared__ __attribute__((aligned(16))) float  ldsA[2][64 * 64];  // 32 KB
  __shared__ __attribute__((aligned(16))) __bf16 ldsB[2][96 * 64];  // 24 KB

  const int tid  = threadIdx.x;
  const int w    = tid >> 6, lane = tid & 63;
  const int l15  = lane & 15, l4 = lane >> 4;
  const int wr   = w >> 1, wc = w & 1;          // wave tile 32r x 48c

  // XCD-chunked bijective swizzle (512 = 8*64), rtile-major within XCD
  const int id   = blockIdx.x;
  const int swz  = (id & 7) * 64 + (id >> 3);
  const int rt   = swz >> 2, ct = swz & 3;
  const int row0 = rt * 64;                     // flat row [0,8192)
  const int g0   = ct * 96;                     // col base [0,384)

  // ---- staging addresses, SOURCE-swizzled ----
  // A: dest row r = w*16 + j*4 + (lane>>4); r&7 = (j&1)*4 + (lane>>4).
  const int aRow = lane >> 4;
  const int aPos = lane & 15;
  const int cE   = aPos ^ aRow;                 // j even
  const int cO   = aPos ^ (4 | aRow);           // j odd
  const float* gAe = x + (size_t)(row0 + w * 16 + aRow) * DD + cE * 4;
  const float* gAo = x + (size_t)(row0 + w * 16 + aRow) * DD + cO * 4;
  // B: dest row r = w*24 + j*8 + (lane>>3); r&7 = lane>>3 (24,8 ≡ 0 mod 8).
  const int bRow = lane >> 3;
  const int cB   = (lane & 7) ^ bRow;
  const __bf16* gB = Wb + (size_t)(g0 + w * 24 + bRow) * DD + cB * 8;

  f32x4 acc[2][3] = {};

#define STAGE(P, T) {                                                        \
    const int k0_ = (T) * 64;                                                \
    gload16(gAe + k0_,                    &ldsA[P][(w * 16 +  0) * 64]);     \
    gload16(gAo + k0_ + (size_t) 4 * DD,  &ldsA[P][(w * 16 +  4) * 64]);     \
    gload16(gAe + k0_ + (size_t) 8 * DD,  &ldsA[P][(w * 16 +  8) * 64]);     \
    gload16(gAo + k0_ + (size_t)12 * DD,  &ldsA[P][(w * 16 + 12) * 64]);     \
    gload16(gB  + k0_,                    &ldsB[P][(w * 24 +  0) * 64]);     \
    gload16(gB  + k0_ + (size_t) 8 * DD,  &ldsB[P][(w * 24 +  8) * 64]);     \
    gload16(gB  + k0_ + (size_t)16 * DD,  &ldsB[P][(w * 24 + 16) * 64]);     }

#define CVT8(LO, HI) (bf16x8){ (__bf16)(LO)[0], (__bf16)(LO)[1],             \
    (__bf16)(LO)[2], (__bf16)(LO)[3], (__bf16)(HI)[0], (__bf16)(HI)[1],      \
    (__bf16)(HI)[2], (__bf16)(HI)[3] }

#define COMPUTE(P) {                                                         \
    const int rs7 = l15 & 7;                                                 \
    _Pragma("unroll") for (int ks = 0; ks < 2; ++ks) {                       \
      bf16x8 af[2], bq[3];                                                   \
      _Pragma("unroll") for (int m = 0; m < 2; ++m) {                        \
        const int row = wr * 32 + m * 16 + l15;                              \
        const int c0 = ks * 8 + l4 * 2;                                      \
        f32x4 lo = *(const f32x4*)&ldsA[P][row * 64 + (( c0      ^ rs7) << 2)]; \
        f32x4 hi = *(const f32x4*)&ldsA[P][row * 64 + (((c0 + 1) ^ rs7) << 2)]; \
        af[m] = CVT8(lo, hi);                                                \
      }                                                                      \
      _Pragma("unroll") for (int n = 0; n < 3; ++n) {                        \
        const int row = wc * 48 + n * 16 + l15;                              \
        bq[n] = *(const bf16x8*)&ldsB[P][row * 64 + (((ks*4 + l4) ^ rs7) << 3)]; \
      }                                                                      \
      _Pragma("unroll") for (int m = 0; m < 2; ++m)                          \
        _Pragma("unroll") for (int n = 0; n < 3; ++n)                        \
          acc[m][n] = __builtin_amdgcn_mfma_f32_16x16x32_bf16(               \
              af[m], bq[n], acc[m][n], 0, 0, 0);                             \
    } }

  STAGE(0, 0);
  __syncthreads();
  for (int t = 0; t < 15; ++t) {
    STAGE((t + 1) & 1, t + 1);
    COMPUTE(t & 1);
    __syncthreads();
  }
  COMPUTE(1);
  __syncthreads();
#undef STAGE
#undef CVT8
#undef COMPUTE

  __bf16* Tb = (__bf16*)ldsA;                  // [96 cols][64 rows chunkXOR] 12KB
  #pragma unroll
  for (int m = 0; m < 2; ++m)
    #pragma unroll
    for (int n = 0; n < 3; ++n) {
      const int colg = g0 + wc * 48 + n * 16 + l15;
      if (colg < 128) {                        // Q: row-major store
        const float bv = qB[colg];
        #pragma unroll
        for (int r = 0; r < 4; ++r) {
          const int row = row0 + wr * 32 + m * 16 + l4 * 4 + r;
          Qbf[(size_t)row * EE + colg] = (__bf16)(acc[m][n][r] + bv);
        }
      } else {                                 // K/V: stage for transpose
        const float bv = (colg < 256) ? kB[colg - 128] : vB[colg - 256];
        const int tc = wc * 48 + n * 16 + l15; // 0..95
        #pragma unroll
        for (int r = 0; r < 4; ++r) {
          const int rl = wr * 32 + m * 16 + l4 * 4 + r;
          Tb[tc * 64 + (((rl >> 3) ^ (tc & 7)) << 3) + (rl & 7)] =
              (__bf16)(acc[m][n][r] + bv);
        }
      }
    }
  __syncthreads();
  {
    const int bb = row0 >> 12, s0v = row0 & 4095;
    for (int idx = tid; idx < 96 * 4; idx += 256) {
      const int tc = idx >> 2, p2 = idx & 3;
      const int colg = g0 + tc;
      if (colg >= 128) {
        const int cl = colg & 127;
        __bf16* dst = ((colg < 256) ? KT : VT) + ((size_t)bb * EE + cl) * SS + s0v;
        #pragma unroll
        for (int j = 0; j < 2; ++j) {
          const int ch = p2 * 2 + j;           // 8 chunks of 8 bf16 per col
          bf16x8 v = *(const bf16x8*)&Tb[tc * 64 + ((ch ^ (tc & 7)) << 3)];
          *(bf16x8*)&dst[ch * 8] = v;
        }
      }
    }
  }
}

// ---------------------------------------------------------------------------
// K2: partial K^T V.  grid (64 s-chunks, 2 f-halves, 2 b) x 256 thr = 256
// blocks (1/CU).  Block: 64 s x 128 e x 64 f; wave w owns 16 f.
// ---------------------------------------------------------------------------
__global__ __launch_bounds__(256) void ktv_kernel(
    const __bf16* __restrict__ KT, const __bf16* __restrict__ VT,
    float* __restrict__ part)
{
  const int c = blockIdx.x, fh = blockIdx.y, b = blockIdx.z;
  const int tid = threadIdx.x;
  const int w = tid >> 6, lane = tid & 63;
  const int l15 = lane & 15, l4 = lane >> 4;
  const int s0 = c * 64;
  const int fbase = fh * 64 + w * 16;
  const __bf16* Kb = KT + (size_t)b * EE * SS;
  const __bf16* Vb = VT + (size_t)b * EE * SS;

  f32x4 acc[8] = {};
  #pragma unroll
  for (int ks = 0; ks < 2; ++ks) {
    const int s = s0 + ks * 32 + 8 * l4;
    bf16x8 bv = *(const bf16x8*)&Vb[(size_t)(fbase + l15) * SS + s];
    #pragma unroll
    for (int i = 0; i < 8; ++i) {
      bf16x8 av = *(const bf16x8*)&Kb[(size_t)(i * 16 + l15) * SS + s];
      acc[i] = __builtin_amdgcn_mfma_f32_16x16x32_bf16(av, bv, acc[i], 0, 0, 0);
    }
  }
  float* P = part + (size_t)(b * 64 + c) * 16384;
  #pragma unroll
  for (int i = 0; i < 8; ++i)
    #pragma unroll
    for (int r = 0; r < 4; ++r) {
      int e = i * 16 + l4 * 4 + r;
      int f = fbase + l15;
      P[e * 128 + f] = acc[i][r];
    }
}

// ---------------------------------------------------------------------------
// K3: reduce 64 partials -> MT[b][f][e] = scale * sum.  grid (64,2) x 256.
// Block covers 2 e-rows; threads = 2e x 128f (coalesced across f).
// ---------------------------------------------------------------------------
__global__ __launch_bounds__(256) void reduce_kernel(
    const float* __restrict__ part, __bf16* __restrict__ MT)
{
  const int b = blockIdx.y;
  const int e = blockIdx.x * 2 + (threadIdx.x >> 7);
  const int f = threadIdx.x & 127;
  float s = 0.f;
  for (int cc = 0; cc < 64; ++cc)
    s += part[(size_t)(b * 64 + cc) * 16384 + e * 128 + f];
  MT[((size_t)b * EE + f) * EE + e] = (__bf16)(SCALE * s);
}

// ---------------------------------------------------------------------------
// K4: O = Q * M  (MT[f][e]).  grid (128, 2) x 128 thr (2 waves of 16 rows).
// ---------------------------------------------------------------------------
__global__ __launch_bounds__(128) void qm_kernel(
    const __bf16* __restrict__ Qbf, const __bf16* __restrict__ MT,
    float* __restrict__ out)
{
  const int b = blockIdx.y;
  const int tid = threadIdx.x;
  const int w = tid >> 6, lane = tid & 63;
  const int l15 = lane & 15, l4 = lane >> 4;
  const int row0 = blockIdx.x * 32 + w * 16;
  const __bf16* Qb = Qbf + (size_t)b * SS * EE;
  const __bf16* Mb = MT + (size_t)b * EE * EE;

  f32x4 acc[8] = {};
  #pragma unroll
  for (int ks = 0; ks < 4; ++ks) {
    const int e = ks * 32 + 8 * l4;
    bf16x8 av = *(const bf16x8*)&Qb[(size_t)(row0 + l15) * EE + e];
    #pragma unroll
    for (int j = 0; j < 8; ++j) {
      bf16x8 bv = *(const bf16x8*)&Mb[(size_t)(j * 16 + l15) * EE + e];
      acc[j] = __builtin_amdgcn_mfma_f32_16x16x32_bf16(av, bv, acc[j], 0, 0, 0);
    }
  }
  #pragma unroll
  for (int j = 0; j < 8; ++j)
    #pragma unroll
    for (int r = 0; r < 4; ++r) {
      int srow = row0 + l4 * 4 + r;
      int f = j * 16 + l15;
      out[((size_t)b * SS + srow) * EE + f] = acc[j][r];
    }
}

extern "C" void kernel_launch(void* const* d_in, const int* in_sizes, int n_in,
                              void* d_out, int out_size, void* d_ws, size_t ws_size,
                              hipStream_t stream) {
  const float* x  = (const float*)d_in[0];
  const float* qW = (const float*)d_in[1];
  const float* qB = (const float*)d_in[2];
  const float* kW = (const float*)d_in[3];
  const float* kB = (const float*)d_in[4];
  const float* vW = (const float*)d_in[5];
  const float* vB = (const float*)d_in[6];
  float* out = (float*)d_out;

  char* base = (char*)d_ws;
  __bf16* Wb  = (__bf16*)(base);                         // 768 KB
  __bf16* Qbf = (__bf16*)(base + (1u  << 20));           // 2 MB
  __bf16* KT  = (__bf16*)(base + (3u  << 20));           // 2 MB
  __bf16* VT  = (__bf16*)(base + (5u  << 20));           // 2 MB
  float*  part= (float*) (base + (7u  << 20));           // 8 MB
  __bf16* MT  = (__bf16*)(base + (15u << 20));           // 64 KB

  wcast_kernel <<<dim3(64, 3),    256, 0, stream>>>(qW, kW, vW, Wb);
  proj_kernel  <<<dim3(512),      256, 0, stream>>>(x, Wb, qB, kB, vB, Qbf, KT, VT);
  ktv_kernel   <<<dim3(64, 2, 2), 256, 0, stream>>>(KT, VT, part);
  reduce_kernel<<<dim3(64, 2),    256, 0, stream>>>(part, MT);
  qm_kernel    <<<dim3(128, 2),   128, 0, stream>>>(Qbf, MT, out);
}

// Round 9
// 41.720 us; speedup vs baseline: 1.5530x; 1.0238x over previous
//
#include <hip/hip_runtime.h>

#define SS 4096
#define DD 1024
#define EE 128
#define SCALE 0.08838834764831845f   // 1/sqrt(128)

typedef __bf16 bf16x8 __attribute__((ext_vector_type(8)));
typedef float  f32x4  __attribute__((ext_vector_type(4)));

__device__ __forceinline__ void gload16(const void* g, void* l) {
  __builtin_amdgcn_global_load_lds(
      (const __attribute__((address_space(1))) void*)g,
      (__attribute__((address_space(3))) void*)l, 16, 0, 0);
}

// ---------------------------------------------------------------------------
// K0: cast W (q|k|v, each 128x1024 fp32) to bf16 Wb[384][1024].
// ---------------------------------------------------------------------------
__global__ __launch_bounds__(256) void wcast_kernel(
    const float* __restrict__ qW, const float* __restrict__ kW,
    const float* __restrict__ vW, __bf16* __restrict__ Wb)
{
  const int m = blockIdx.y;
  const float* src = (m == 0) ? qW : (m == 1 ? kW : vW);
  const size_t o = ((size_t)blockIdx.x * 256 + threadIdx.x) * 8;
  float4 u0 = *(const float4*)&src[o];
  float4 u1 = *(const float4*)&src[o + 4];
  bf16x8 v = { (__bf16)u0.x, (__bf16)u0.y, (__bf16)u0.z, (__bf16)u0.w,
               (__bf16)u1.x, (__bf16)u1.y, (__bf16)u1.z, (__bf16)u1.w };
  *(bf16x8*)&Wb[(size_t)m * EE * DD + o] = v;
}

// ---------------------------------------------------------------------------
// K1: fused QKV projection.  BM=64 BN=64 BK=64; grid 768 (3 blocks/CU),
// 256 thr (4 waves 2x2, wave 32x32).
// A: reg-staged fp32 -> bf16 -> XOR-swizzled ds_write, 2-tile reg prefetch.
// B: source-swizzled global_load_lds (1-tile prefetch).
// Counted vmcnt + raw s_barrier: loads stay in flight across barriers (T4).
// ctile 0,1 -> Q (+bias, row-major); 2,3 -> KT; 4,5 -> VT (LDS transpose).
// ---------------------------------------------------------------------------
__global__ __launch_bounds__(256, 3) void proj_kernel(
    const float* __restrict__ x, const __bf16* __restrict__ Wb,
    const float* __restrict__ qB, const float* __restrict__ kB,
    const float* __restrict__ vB,
    __bf16* __restrict__ Qbf, __bf16* __restrict__ KT, __bf16* __restrict__ VT)
{
  __shared__ __attribute__((aligned(16))) __bf16 ldsA[2][64 * 64];  // 16 KB
  __shared__ __attribute__((aligned(16))) __bf16 ldsB[2][64 * 64];  // 16 KB

  const int tid  = threadIdx.x;
  const int w    = tid >> 6, lane = tid & 63;
  const int l15  = lane & 15, l4 = lane >> 4;
  const int wr   = w >> 1, wc = w & 1;          // wave tile 32r x 32c

  // XCD-chunked bijective swizzle (768 % 8 == 0), rtile-major within XCD
  const int id   = blockIdx.x;
  const int swz  = (id & 7) * 96 + (id >> 3);
  const int rt   = swz / 6, ct = swz % 6;
  const int row0 = rt * 64;                     // flat row [0,8192)
  const int g0   = ct * 64;                     // col base [0,384)

  // ---- A reg-staging geometry: thread -> (row=tid>>2, seg=tid&3) ----
  const int arow = tid >> 2;                    // 0..63
  const int aseg = tid & 3;                     // 16 floats at k = aseg*16
  const int ars  = arow & 7;
  const float* gA = x + (size_t)(row0 + arow) * DD + aseg * 16;

  // ---- B staging: source-swizzled gload_lds (verified R6/R7) ----
  // dest row r = w*16 + j*8 + (lane>>3); r&7 = lane>>3; src chunk = (lane&7)^r&7
  const int bRow = lane >> 3;
  const int cB   = (lane & 7) ^ bRow;
  const __bf16* gB = Wb + (size_t)(g0 + w * 16 + bRow) * DD + cB * 8;

  f32x4 acc[2][2] = {};
  f32x4 rA0[4], rA1[4];

#define AISSUE(RS, T) {                                                      \
    const float* g_ = gA + (T) * 64;                                         \
    RS[0] = *(const f32x4*)(g_);      RS[1] = *(const f32x4*)(g_ + 4);       \
    RS[2] = *(const f32x4*)(g_ + 8);  RS[3] = *(const f32x4*)(g_ + 12); }

#define AWRITE(P, RS) {                                                      \
    bf16x8 v0_ = { (__bf16)RS[0][0], (__bf16)RS[0][1], (__bf16)RS[0][2],     \
                   (__bf16)RS[0][3], (__bf16)RS[1][0], (__bf16)RS[1][1],     \
                   (__bf16)RS[1][2], (__bf16)RS[1][3] };                     \
    bf16x8 v1_ = { (__bf16)RS[2][0], (__bf16)RS[2][1], (__bf16)RS[2][2],     \
                   (__bf16)RS[2][3], (__bf16)RS[3][0], (__bf16)RS[3][1],     \
                   (__bf16)RS[3][2], (__bf16)RS[3][3] };                     \
    *(bf16x8*)&ldsA[P][arow * 64 + (((aseg * 2)     ^ ars) << 3)] = v0_;     \
    *(bf16x8*)&ldsA[P][arow * 64 + (((aseg * 2 + 1) ^ ars) << 3)] = v1_; }

#define BSTAGE(P, T) {                                                       \
    gload16(gB + (T) * 64,                   &ldsB[P][(w * 16    ) * 64]);   \
    gload16(gB + (T) * 64 + (size_t)8 * DD,  &ldsB[P][(w * 16 + 8) * 64]); }

#define COMPUTE(P) {                                                         \
    const int rs7 = l15 & 7;                                                 \
    _Pragma("unroll") for (int ks = 0; ks < 2; ++ks) {                       \
      const int so = ((ks * 4 + l4) ^ rs7) << 3;                             \
      bf16x8 a0 = *(const bf16x8*)&ldsA[P][(wr * 32      + l15) * 64 + so];  \
      bf16x8 a1 = *(const bf16x8*)&ldsA[P][(wr * 32 + 16 + l15) * 64 + so];  \
      bf16x8 b0 = *(const bf16x8*)&ldsB[P][(wc * 32      + l15) * 64 + so];  \
      bf16x8 b1 = *(const bf16x8*)&ldsB[P][(wc * 32 + 16 + l15) * 64 + so];  \
      acc[0][0] = __builtin_amdgcn_mfma_f32_16x16x32_bf16(a0,b0,acc[0][0],0,0,0); \
      acc[0][1] = __builtin_amdgcn_mfma_f32_16x16x32_bf16(a0,b1,acc[0][1],0,0,0); \
      acc[1][0] = __builtin_amdgcn_mfma_f32_16x16x32_bf16(a1,b0,acc[1][0],0,0,0); \
      acc[1][1] = __builtin_amdgcn_mfma_f32_16x16x32_bf16(a1,b1,acc[1][1],0,0,0); \
    } }

#define HEADBAR(VN) {                                                        \
    asm volatile("s_waitcnt vmcnt(" #VN ") lgkmcnt(0)" ::: "memory");        \
    __builtin_amdgcn_s_barrier();                                            \
    asm volatile("" ::: "memory"); }

  // ---- prologue: A(0)->rA0, B(0), A(1)->rA1, write A(0) ----
  AISSUE(rA0, 0);
  BSTAGE(0, 0);
  __builtin_amdgcn_sched_barrier(0);
  AISSUE(rA1, 1);
  __builtin_amdgcn_sched_barrier(0);
  AWRITE(0, rA0);                       // compiler auto-waits rA0's loads

  // ---- main loop, unrolled x2 for static reg-set names ----
  // steady invariant at head: outstanding = B(t)*2 + A(t+1)*4 = 6
  for (int t = 0; t < 14; t += 2) {
    // sub-iter tile t (buf 0): stage B(t+1)->buf1, issue A(t+2)->rA0, write A(t+1)
    HEADBAR(4);                          // drain B(t), keep A(t+1) in flight
    COMPUTE(0);
    BSTAGE(1, t + 1);
    __builtin_amdgcn_sched_barrier(0);
    AISSUE(rA0, t + 2);
    __builtin_amdgcn_sched_barrier(0);
    AWRITE(1, rA1);                      // auto vmcnt(6): A(t+1) landed
    // sub-iter tile t+1 (buf 1)
    HEADBAR(4);
    COMPUTE(1);
    BSTAGE(0, t + 2);
    __builtin_amdgcn_sched_barrier(0);
    AISSUE(rA1, t + 3);
    __builtin_amdgcn_sched_barrier(0);
    AWRITE(0, rA0);                      // A(t+2)
  }
  // t = 14 (buf 0): stage B(15), no A(16)
  HEADBAR(4);
  COMPUTE(0);
  BSTAGE(1, 15);
  __builtin_amdgcn_sched_barrier(0);
  AWRITE(1, rA1);                        // A(15); auto vmcnt(2)
  // t = 15 (buf 1): drain B(15)
  HEADBAR(0);
  COMPUTE(1);
#undef AISSUE
#undef AWRITE
#undef BSTAGE
#undef COMPUTE
#undef HEADBAR
  __syncthreads();

  const float* bias = (g0 < 128) ? qB : (g0 < 256 ? kB : vB);
  const int bofs = (g0 < 128) ? g0 : (g0 < 256 ? g0 - 128 : g0 - 256);

  if (ct < 2) {                                  // Q: row-major store
    #pragma unroll
    for (int m = 0; m < 2; ++m)
      #pragma unroll
      for (int n = 0; n < 2; ++n) {
        const int col = wc * 32 + n * 16 + l15;
        const float bv = bias[bofs + col];
        #pragma unroll
        for (int r = 0; r < 4; ++r) {
          const int row = row0 + wr * 32 + m * 16 + l4 * 4 + r;
          Qbf[(size_t)row * EE + g0 + col] = (__bf16)(acc[m][n][r] + bv);
        }
      }
  } else {                                       // K/V: transpose via LDS
    __bf16* Tb = (__bf16*)ldsA;                  // [64 cols][64 rows chunkXOR]
    #pragma unroll
    for (int m = 0; m < 2; ++m)
      #pragma unroll
      for (int n = 0; n < 2; ++n) {
        const int tc = wc * 32 + n * 16 + l15;
        const float bv = bias[bofs + tc];
        #pragma unroll
        for (int r = 0; r < 4; ++r) {
          const int rl = wr * 32 + m * 16 + l4 * 4 + r;
          Tb[tc * 64 + (((rl >> 3) ^ (tc & 7)) << 3) + (rl & 7)] =
              (__bf16)(acc[m][n][r] + bv);
        }
      }
    __syncthreads();
    const int col = tid >> 2, p2 = tid & 3;      // 64 cols x 4 thr
    const int b = row0 >> 12, s0 = row0 & 4095;
    __bf16* dst = (ct < 4)
        ? &KT[((size_t)b * EE + (ct - 2) * 64 + col) * SS + s0]
        : &VT[((size_t)b * EE + (ct - 4) * 64 + col) * SS + s0];
    #pragma unroll
    for (int j = 0; j < 2; ++j) {
      const int ch = p2 * 2 + j;                 // 8 chunks of 8 bf16
      bf16x8 v = *(const bf16x8*)&Tb[col * 64 + ((ch ^ (col & 7)) << 3)];
      *(bf16x8*)&dst[ch * 8] = v;
    }
  }
}

// ---------------------------------------------------------------------------
// K2: partial K^T V.  grid (64 s-chunks, 2 f-halves, 2 b) x 256 thr.
// ---------------------------------------------------------------------------
__global__ __launch_bounds__(256) void ktv_kernel(
    const __bf16* __restrict__ KT, const __bf16* __restrict__ VT,
    float* __restrict__ part)
{
  const int c = blockIdx.x, fh = blockIdx.y, b = blockIdx.z;
  const int tid = threadIdx.x;
  const int w = tid >> 6, lane = tid & 63;
  const int l15 = lane & 15, l4 = lane >> 4;
  const int s0 = c * 64;
  const int fbase = fh * 64 + w * 16;
  const __bf16* Kb = KT + (size_t)b * EE * SS;
  const __bf16* Vb = VT + (size_t)b * EE * SS;

  f32x4 acc[8] = {};
  #pragma unroll
  for (int ks = 0; ks < 2; ++ks) {
    const int s = s0 + ks * 32 + 8 * l4;
    bf16x8 bv = *(const bf16x8*)&Vb[(size_t)(fbase + l15) * SS + s];
    #pragma unroll
    for (int i = 0; i < 8; ++i) {
      bf16x8 av = *(const bf16x8*)&Kb[(size_t)(i * 16 + l15) * SS + s];
      acc[i] = __builtin_amdgcn_mfma_f32_16x16x32_bf16(av, bv, acc[i], 0, 0, 0);
    }
  }
  float* P = part + (size_t)(b * 64 + c) * 16384;
  #pragma unroll
  for (int i = 0; i < 8; ++i)
    #pragma unroll
    for (int r = 0; r < 4; ++r) {
      int e = i * 16 + l4 * 4 + r;
      int f = fbase + l15;
      P[e * 128 + f] = acc[i][r];
    }
}

// ---------------------------------------------------------------------------
// K3: reduce 64 partials -> MT[b][f][e] = scale * sum.  grid (64,2) x 256.
// ---------------------------------------------------------------------------
__global__ __launch_bounds__(256) void reduce_kernel(
    const float* __restrict__ part, __bf16* __restrict__ MT)
{
  const int b = blockIdx.y;
  const int e = blockIdx.x * 2 + (threadIdx.x >> 7);
  const int f = threadIdx.x & 127;
  float s = 0.f;
  for (int cc = 0; cc < 64; ++cc)
    s += part[(size_t)(b * 64 + cc) * 16384 + e * 128 + f];
  MT[((size_t)b * EE + f) * EE + e] = (__bf16)(SCALE * s);
}

// ---------------------------------------------------------------------------
// K4: O = Q * M  (MT[f][e]).  grid (128, 2) x 128 thr.
// ---------------------------------------------------------------------------
__global__ __launch_bounds__(128) void qm_kernel(
    const __bf16* __restrict__ Qbf, const __bf16* __restrict__ MT,
    float* __restrict__ out)
{
  const int b = blockIdx.y;
  const int tid = threadIdx.x;
  const int w = tid >> 6, lane = tid & 63;
  const int l15 = lane & 15, l4 = lane >> 4;
  const int row0 = blockIdx.x * 32 + w * 16;
  const __bf16* Qb = Qbf + (size_t)b * SS * EE;
  const __bf16* Mb = MT + (size_t)b * EE * EE;

  f32x4 acc[8] = {};
  #pragma unroll
  for (int ks = 0; ks < 4; ++ks) {
    const int e = ks * 32 + 8 * l4;
    bf16x8 av = *(const bf16x8*)&Qb[(size_t)(row0 + l15) * EE + e];
    #pragma unroll
    for (int j = 0; j < 8; ++j) {
      bf16x8 bv = *(const bf16x8*)&Mb[(size_t)(j * 16 + l15) * EE + e];
      acc[j] = __builtin_amdgcn_mfma_f32_16x16x32_bf16(av, bv, acc[j], 0, 0, 0);
    }
  }
  #pragma unroll
  for (int j = 0; j < 8; ++j)
    #pragma unroll
    for (int r = 0; r < 4; ++r) {
      int srow = row0 + l4 * 4 + r;
      int f = j * 16 + l15;
      out[((size_t)b * SS + srow) * EE + f] = acc[j][r];
    }
}

extern "C" void kernel_launch(void* const* d_in, const int* in_sizes, int n_in,
                              void* d_out, int out_size, void* d_ws, size_t ws_size,
                              hipStream_t stream) {
  const float* x  = (const float*)d_in[0];
  const float* qW = (const float*)d_in[1];
  const float* qB = (const float*)d_in[2];
  const float* kW = (const float*)d_in[3];
  const float* kB = (const float*)d_in[4];
  const float* vW = (const float*)d_in[5];
  const float* vB = (const float*)d_in[6];
  float* out = (float*)d_out;

  char* base = (char*)d_ws;
  __bf16* Wb  = (__bf16*)(base);                         // 768 KB
  __bf16* Qbf = (__bf16*)(base + (1u  << 20));           // 2 MB
  __bf16* KT  = (__bf16*)(base + (3u  << 20));           // 2 MB
  __bf16* VT  = (__bf16*)(base + (5u  << 20));           // 2 MB
  float*  part= (float*) (base + (7u  << 20));           // 8 MB
  __bf16* MT  = (__bf16*)(base + (15u << 20));           // 64 KB

  wcast_kernel <<<dim3(64, 3),    256, 0, stream>>>(qW, kW, vW, Wb);
  proj_kernel  <<<dim3(768),      256, 0, stream>>>(x, Wb, qB, kB, vB, Qbf, KT, VT);
  ktv_kernel   <<<dim3(64, 2, 2), 256, 0, stream>>>(KT, VT, part);
  reduce_kernel<<<dim3(64, 2),    256, 0, stream>>>(part, MT);
  qm_kernel    <<<dim3(128, 2),   128, 0, stream>>>(Qbf, MT, out);
}

// Round 10
// 41.081 us; speedup vs baseline: 1.5771x; 1.0156x over previous
//
#include <hip/hip_runtime.h>

#define SS 4096
#define DD 1024
#define EE 128
#define SCALE 0.08838834764831845f   // 1/sqrt(128)

typedef __bf16 bf16x8 __attribute__((ext_vector_type(8)));
typedef __bf16 bf16x4 __attribute__((ext_vector_type(4)));
typedef float  f32x4  __attribute__((ext_vector_type(4)));

__device__ __forceinline__ void gload16(const void* g, void* l) {
  __builtin_amdgcn_global_load_lds(
      (const __attribute__((address_space(1))) void*)g,
      (__attribute__((address_space(3))) void*)l, 16, 0, 0);
}

// ---------------------------------------------------------------------------
// K0: cast W (q|k|v, each 128x1024 fp32) to bf16 Wb[384][1024].
// ---------------------------------------------------------------------------
__global__ __launch_bounds__(256) void wcast_kernel(
    const float* __restrict__ qW, const float* __restrict__ kW,
    const float* __restrict__ vW, __bf16* __restrict__ Wb)
{
  const int m = blockIdx.y;
  const float* src = (m == 0) ? qW : (m == 1 ? kW : vW);
  const size_t o = ((size_t)blockIdx.x * 256 + threadIdx.x) * 8;
  float4 u0 = *(const float4*)&src[o];
  float4 u1 = *(const float4*)&src[o + 4];
  bf16x8 v = { (__bf16)u0.x, (__bf16)u0.y, (__bf16)u0.z, (__bf16)u0.w,
               (__bf16)u1.x, (__bf16)u1.y, (__bf16)u1.z, (__bf16)u1.w };
  *(bf16x8*)&Wb[(size_t)m * EE * DD + o] = v;
}

// ---------------------------------------------------------------------------
// K1: fused QKV projection.  BM=64 BN=64 BK=64; grid 768 (3 blocks/CU),
// 128 thr (2 waves, wave-tile 64 rows x 32 cols: 12 LDS reads / 16 MFMA).
// A: reg-staged fp32 (4KB-contiguous wave loads) -> bf16 -> swizzled ds_write,
//    2-tile reg prefetch.  B: source-swizzled global_load_lds, 1-tile dbuf.
// Counted vmcnt + raw s_barrier (loads in flight across barriers).
// Q epilogue folds *SCALE into Qbf.
// ---------------------------------------------------------------------------
__global__ __launch_bounds__(128, 2) void proj_kernel(
    const float* __restrict__ x, const __bf16* __restrict__ Wb,
    const float* __restrict__ qB, const float* __restrict__ kB,
    const float* __restrict__ vB,
    __bf16* __restrict__ Qbf, __bf16* __restrict__ KT, __bf16* __restrict__ VT)
{
  __shared__ __attribute__((aligned(16))) __bf16 ldsA[2][64 * 64];  // 16 KB
  __shared__ __attribute__((aligned(16))) __bf16 ldsB[2][64 * 64];  // 16 KB

  const int tid  = threadIdx.x;
  const int w    = tid >> 6, lane = tid & 63;
  const int l15  = lane & 15, l4 = lane >> 4;

  // XCD-chunked bijective swizzle (768 % 8 == 0), rtile-major within XCD
  const int id   = blockIdx.x;
  const int swz  = (id & 7) * 96 + (id >> 3);
  const int rt   = swz / 6, ct = swz % 6;
  const int row0 = rt * 64;                     // flat row [0,8192)
  const int g0   = ct * 64;                     // col base [0,384)

  // ---- A reg-staging: instr j covers rows j*8+w*4+(lane>>4), 4KB contiguous
  const int arow0 = w * 4 + (lane >> 4);        // row base for j=0 (step 8)
  const int acolv = lane & 15;                  // f32x4 index within row
  const float* gA = x + (size_t)(row0 + arow0) * DD + acolv * 4;
  // write-side: chunk cc = acolv>>1 (16B), half = acolv&1 (8B within chunk)
  const int acc16 = acolv >> 1, ahalf = acolv & 1;

  // ---- B staging: dest row r = w*32 + j*8 + (lane>>3); r&7 = lane>>3
  const int bRow = lane >> 3;
  const int cB   = (lane & 7) ^ bRow;
  const __bf16* gB = Wb + (size_t)(g0 + w * 32 + bRow) * DD + cB * 8;

  f32x4 acc[4][2] = {};
  f32x4 rA0[8], rA1[8];

#define AISSUE(RS, T) {                                                      \
    const float* g_ = gA + (T) * 64;                                         \
    _Pragma("unroll") for (int j = 0; j < 8; ++j)                            \
      RS[j] = *(const f32x4*)(g_ + (size_t)j * 8 * DD);                      }

#define AWRITE(P, RS) {                                                      \
    _Pragma("unroll") for (int j = 0; j < 8; ++j) {                          \
      bf16x4 v_ = { (__bf16)RS[j][0], (__bf16)RS[j][1],                      \
                    (__bf16)RS[j][2], (__bf16)RS[j][3] };                    \
      const int r_ = arow0 + j * 8;                                          \
      *(bf16x4*)&ldsA[P][r_ * 64 + (((acc16 ^ (r_ & 7)) << 3) + ahalf * 4)]  \
          = v_;                                                              \
    } }

#define BSTAGE(P, T) {                                                       \
    _Pragma("unroll") for (int j = 0; j < 4; ++j)                            \
      gload16(gB + (T) * 64 + (size_t)j * 8 * DD,                            \
              &ldsB[P][(w * 32 + j * 8) * 64]);                              }

#define COMPUTE(P) {                                                         \
    const int rs7 = l15 & 7;                                                 \
    _Pragma("unroll") for (int ks = 0; ks < 2; ++ks) {                       \
      const int so = ((ks * 4 + l4) ^ rs7) << 3;                             \
      bf16x8 af[4], bq[2];                                                   \
      _Pragma("unroll") for (int m = 0; m < 4; ++m)                          \
        af[m] = *(const bf16x8*)&ldsA[P][(m * 16 + l15) * 64 + so];          \
      _Pragma("unroll") for (int n = 0; n < 2; ++n)                          \
        bq[n] = *(const bf16x8*)&ldsB[P][(w * 32 + n * 16 + l15) * 64 + so]; \
      _Pragma("unroll") for (int m = 0; m < 4; ++m)                          \
        _Pragma("unroll") for (int n = 0; n < 2; ++n)                        \
          acc[m][n] = __builtin_amdgcn_mfma_f32_16x16x32_bf16(               \
              af[m], bq[n], acc[m][n], 0, 0, 0);                             \
    } }

#define HEADBAR(VN) {                                                        \
    asm volatile("s_waitcnt vmcnt(" #VN ") lgkmcnt(0)" ::: "memory");        \
    __builtin_amdgcn_s_barrier();                                            \
    asm volatile("" ::: "memory"); }

  // ---- prologue ----
  AISSUE(rA0, 0);
  BSTAGE(0, 0);
  __builtin_amdgcn_sched_barrier(0);
  AISSUE(rA1, 1);
  __builtin_amdgcn_sched_barrier(0);
  AWRITE(0, rA0);                        // auto-wait drains A(0)

  // steady head invariant: outstanding = B(t)*4 + A(t+1)*8 = 12
  for (int t = 0; t < 14; t += 2) {
    HEADBAR(8);                          // drain B(t), keep A(t+1)
    COMPUTE(0);
    BSTAGE(1, t + 1);
    __builtin_amdgcn_sched_barrier(0);
    AISSUE(rA0, t + 2);
    __builtin_amdgcn_sched_barrier(0);
    AWRITE(1, rA1);                      // auto vmcnt(12): A(t+1) landed
    HEADBAR(8);
    COMPUTE(1);
    BSTAGE(0, t + 2);
    __builtin_amdgcn_sched_barrier(0);
    AISSUE(rA1, t + 3);
    __builtin_amdgcn_sched_barrier(0);
    AWRITE(0, rA0);                      // A(t+2)
  }
  HEADBAR(8);                            // t=14
  COMPUTE(0);
  BSTAGE(1, 15);
  __builtin_amdgcn_sched_barrier(0);
  AWRITE(1, rA1);                        // A(15); auto vmcnt(4)
  HEADBAR(0);                            // t=15: drain B(15)
  COMPUTE(1);
#undef AISSUE
#undef AWRITE
#undef BSTAGE
#undef COMPUTE
#undef HEADBAR
  __syncthreads();

  const float* bias = (g0 < 128) ? qB : (g0 < 256 ? kB : vB);
  const int bofs = (g0 < 128) ? g0 : (g0 < 256 ? g0 - 128 : g0 - 256);

  if (ct < 2) {                                  // Q: row-major, *SCALE folded
    #pragma unroll
    for (int m = 0; m < 4; ++m)
      #pragma unroll
      for (int n = 0; n < 2; ++n) {
        const int col = w * 32 + n * 16 + l15;
        const float bv = bias[bofs + col];
        #pragma unroll
        for (int r = 0; r < 4; ++r) {
          const int row = row0 + m * 16 + l4 * 4 + r;
          Qbf[(size_t)row * EE + g0 + col] =
              (__bf16)((acc[m][n][r] + bv) * SCALE);
        }
      }
  } else {                                       // K/V: transpose via LDS
    __bf16* Tb = (__bf16*)ldsA;                  // [64 cols][64 rows chunkXOR]
    #pragma unroll
    for (int m = 0; m < 4; ++m)
      #pragma unroll
      for (int n = 0; n < 2; ++n) {
        const int tc = w * 32 + n * 16 + l15;
        const float bv = bias[bofs + tc];
        #pragma unroll
        for (int r = 0; r < 4; ++r) {
          const int rl = m * 16 + l4 * 4 + r;
          Tb[tc * 64 + (((rl >> 3) ^ (tc & 7)) << 3) + (rl & 7)] =
              (__bf16)(acc[m][n][r] + bv);
        }
      }
    __syncthreads();
    const int col = tid >> 1, p2 = tid & 1;      // 64 cols x 2 thr
    const int b = row0 >> 12, s0 = row0 & 4095;
    __bf16* dst = (ct < 4)
        ? &KT[((size_t)b * EE + (ct - 2) * 64 + col) * SS + s0]
        : &VT[((size_t)b * EE + (ct - 4) * 64 + col) * SS + s0];
    #pragma unroll
    for (int j = 0; j < 4; ++j) {
      const int ch = p2 * 4 + j;                 // 8 chunks of 8 bf16
      bf16x8 v = *(const bf16x8*)&Tb[col * 64 + ((ch ^ (col & 7)) << 3)];
      *(bf16x8*)&dst[ch * 8] = v;
    }
  }
}

// ---------------------------------------------------------------------------
// K2: partial K^T V.  grid (64 s-chunks, 2 f-halves, 2 b) x 256 thr.
// ---------------------------------------------------------------------------
__global__ __launch_bounds__(256) void ktv_kernel(
    const __bf16* __restrict__ KT, const __bf16* __restrict__ VT,
    float* __restrict__ part)
{
  const int c = blockIdx.x, fh = blockIdx.y, b = blockIdx.z;
  const int tid = threadIdx.x;
  const int w = tid >> 6, lane = tid & 63;
  const int l15 = lane & 15, l4 = lane >> 4;
  const int s0 = c * 64;
  const int fbase = fh * 64 + w * 16;
  const __bf16* Kb = KT + (size_t)b * EE * SS;
  const __bf16* Vb = VT + (size_t)b * EE * SS;

  f32x4 acc[8] = {};
  #pragma unroll
  for (int ks = 0; ks < 2; ++ks) {
    const int s = s0 + ks * 32 + 8 * l4;
    bf16x8 bv = *(const bf16x8*)&Vb[(size_t)(fbase + l15) * SS + s];
    #pragma unroll
    for (int i = 0; i < 8; ++i) {
      bf16x8 av = *(const bf16x8*)&Kb[(size_t)(i * 16 + l15) * SS + s];
      acc[i] = __builtin_amdgcn_mfma_f32_16x16x32_bf16(av, bv, acc[i], 0, 0, 0);
    }
  }
  float* P = part + (size_t)(b * 64 + c) * 16384;
  #pragma unroll
  for (int i = 0; i < 8; ++i)
    #pragma unroll
    for (int r = 0; r < 4; ++r) {
      int e = i * 16 + l4 * 4 + r;
      int f = fbase + l15;
      P[e * 128 + f] = acc[i][r];
    }
}

// ---------------------------------------------------------------------------
// K3: reduce 64 partials -> MT[b][f][e] = sum (bf16, transposed; no scale —
// scale folded into Qbf).  grid (64,2) x 256.
// ---------------------------------------------------------------------------
__global__ __launch_bounds__(256) void reduce_kernel(
    const float* __restrict__ part, __bf16* __restrict__ MT)
{
  const int b = blockIdx.y;
  const int e = blockIdx.x * 2 + (threadIdx.x >> 7);
  const int f = threadIdx.x & 127;
  float s = 0.f;
  for (int cc = 0; cc < 64; ++cc)
    s += part[(size_t)(b * 64 + cc) * 16384 + e * 128 + f];
  MT[((size_t)b * EE + f) * EE + e] = (__bf16)s;
}

// ---------------------------------------------------------------------------
// K4: O = Q * M  (MT[f][e]).  grid (128, 2) x 128 thr.
// ---------------------------------------------------------------------------
__global__ __launch_bounds__(128) void qm_kernel(
    const __bf16* __restrict__ Qbf, const __bf16* __restrict__ MT,
    float* __restrict__ out)
{
  const int b = blockIdx.y;
  const int tid = threadIdx.x;
  const int w = tid >> 6, lane = tid & 63;
  const int l15 = lane & 15, l4 = lane >> 4;
  const int row0 = blockIdx.x * 32 + w * 16;
  const __bf16* Qb = Qbf + (size_t)b * SS * EE;
  const __bf16* Mb = MT + (size_t)b * EE * EE;

  f32x4 acc[8] = {};
  #pragma unroll
  for (int ks = 0; ks < 4; ++ks) {
    const int e = ks * 32 + 8 * l4;
    bf16x8 av = *(const bf16x8*)&Qb[(size_t)(row0 + l15) * EE + e];
    #pragma unroll
    for (int j = 0; j < 8; ++j) {
      bf16x8 bv = *(const bf16x8*)&Mb[(size_t)(j * 16 + l15) * EE + e];
      acc[j] = __builtin_amdgcn_mfma_f32_16x16x32_bf16(av, bv, acc[j], 0, 0, 0);
    }
  }
  #pragma unroll
  for (int j = 0; j < 8; ++j)
    #pragma unroll
    for (int r = 0; r < 4; ++r) {
      int srow = row0 + l4 * 4 + r;
      int f = j * 16 + l15;
      out[((size_t)b * SS + srow) * EE + f] = acc[j][r];
    }
}

extern "C" void kernel_launch(void* const* d_in, const int* in_sizes, int n_in,
                              void* d_out, int out_size, void* d_ws, size_t ws_size,
                              hipStream_t stream) {
  const float* x  = (const float*)d_in[0];
  const float* qW = (const float*)d_in[1];
  const float* qB = (const float*)d_in[2];
  const float* kW = (const float*)d_in[3];
  const float* kB = (const float*)d_in[4];
  const float* vW = (const float*)d_in[5];
  const float* vB = (const float*)d_in[6];
  float* out = (float*)d_out;

  char* base = (char*)d_ws;
  __bf16* Wb  = (__bf16*)(base);                         // 768 KB
  __bf16* Qbf = (__bf16*)(base + (1u  << 20));           // 2 MB
  __bf16* KT  = (__bf16*)(base + (3u  << 20));           // 2 MB
  __bf16* VT  = (__bf16*)(base + (5u  << 20));           // 2 MB
  float*  part= (float*) (base + (7u  << 20));           // 8 MB
  __bf16* MT  = (__bf16*)(base + (15u << 20));           // 64 KB

  wcast_kernel <<<dim3(64, 3),    256, 0, stream>>>(qW, kW, vW, Wb);
  proj_kernel  <<<dim3(768),      128, 0, stream>>>(x, Wb, qB, kB, vB, Qbf, KT, VT);
  ktv_kernel   <<<dim3(64, 2, 2), 256, 0, stream>>>(KT, VT, part);
  reduce_kernel<<<dim3(64, 2),    256, 0, stream>>>(part, MT);
  qm_kernel    <<<dim3(128, 2),   128, 0, stream>>>(Qbf, MT, out);
}